// Round 3
// baseline (214.494 us; speedup 1.0000x reference)
//
#include <hip/hip_runtime.h>

// Chamfer distance: B=4, N=M=8192, D=3, fp32. VALU issue-bound.
// Targets packed (x,y,z,|t|^2) in LDS, read via broadcast ds_read_b128.
// 2 queries/thread amortize each LDS read; score = fma chain (3/pair).
// Split-K style partial mins stored per split -> no atomics, no memset.

#define B_ 4
#define N_ 8192
#define QPT 2            // queries per thread
#define THREADS 256

// grid: (N/(THREADS*QPT), S, 2*B). Dynamic LDS: (N/S) float4.
__global__ __launch_bounds__(THREADS) void chamfer_min2(
    const float* __restrict__ pred, const float* __restrict__ gt,
    float* __restrict__ partial) {
  extern __shared__ float4 sh[];
  const int S = gridDim.y;
  const int TPB = N_ / S;                 // targets staged per block
  const int dirb = blockIdx.z;            // 0..7
  const int dir = dirb >> 2;              // 0: pred->gt, 1: gt->pred
  const int b = dirb & 3;

  const float* qsrc = (dir == 0 ? pred : gt) + (size_t)b * N_ * 3;
  const float* tsrc = (dir == 0 ? gt : pred) + (size_t)b * N_ * 3;

  // ---- stage TPB packed targets into LDS (compute |t|^2 on the fly) ----
  const float* tb = tsrc + (size_t)blockIdx.y * TPB * 3;
  for (int g = 0; g < TPB; g += 1024) {
    const int p0 = g + threadIdx.x * 4;   // this thread's 4 points
    const float4 f0 = *(const float4*)(tb + 3 * p0);
    const float4 f1 = *(const float4*)(tb + 3 * p0 + 4);
    const float4 f2 = *(const float4*)(tb + 3 * p0 + 8);
    sh[p0 + 0] = make_float4(f0.x, f0.y, f0.z,
                             fmaf(f0.x, f0.x, fmaf(f0.y, f0.y, f0.z * f0.z)));
    sh[p0 + 1] = make_float4(f0.w, f1.x, f1.y,
                             fmaf(f0.w, f0.w, fmaf(f1.x, f1.x, f1.y * f1.y)));
    sh[p0 + 2] = make_float4(f1.z, f1.w, f2.x,
                             fmaf(f1.z, f1.z, fmaf(f1.w, f1.w, f2.x * f2.x)));
    sh[p0 + 3] = make_float4(f2.y, f2.z, f2.w,
                             fmaf(f2.y, f2.y, fmaf(f2.z, f2.z, f2.w * f2.w)));
  }
  __syncthreads();

  // ---- two queries per thread ----
  const int qi0 = blockIdx.x * (THREADS * QPT) + threadIdx.x;
  const int qi1 = qi0 + THREADS;
  const float ax = qsrc[3 * qi0], ay = qsrc[3 * qi0 + 1], az = qsrc[3 * qi0 + 2];
  const float cx = qsrc[3 * qi1], cy = qsrc[3 * qi1 + 1], cz = qsrc[3 * qi1 + 2];
  const float a0 = -2.0f * ax, a1 = -2.0f * ay, a2 = -2.0f * az;
  const float c0 = -2.0f * cx, c1 = -2.0f * cy, c2 = -2.0f * cz;
  const float aq2 = fmaf(ax, ax, fmaf(ay, ay, az * az));
  const float cq2 = fmaf(cx, cx, fmaf(cy, cy, cz * cz));

  float b00 = 3.4e38f, b01 = 3.4e38f;    // query0: two accumulators (ILP)
  float b10 = 3.4e38f, b11 = 3.4e38f;    // query1

#pragma unroll 2
  for (int j = 0; j < TPB; j += 4) {
    const float4 t0 = sh[j + 0];
    const float4 t1 = sh[j + 1];
    const float4 t2 = sh[j + 2];
    const float4 t3 = sh[j + 3];
    const float sa0 = fmaf(a0, t0.x, fmaf(a1, t0.y, fmaf(a2, t0.z, t0.w)));
    const float sa1 = fmaf(a0, t1.x, fmaf(a1, t1.y, fmaf(a2, t1.z, t1.w)));
    const float sa2 = fmaf(a0, t2.x, fmaf(a1, t2.y, fmaf(a2, t2.z, t2.w)));
    const float sa3 = fmaf(a0, t3.x, fmaf(a1, t3.y, fmaf(a2, t3.z, t3.w)));
    const float sc0 = fmaf(c0, t0.x, fmaf(c1, t0.y, fmaf(c2, t0.z, t0.w)));
    const float sc1 = fmaf(c0, t1.x, fmaf(c1, t1.y, fmaf(c2, t1.z, t1.w)));
    const float sc2 = fmaf(c0, t2.x, fmaf(c1, t2.y, fmaf(c2, t2.z, t2.w)));
    const float sc3 = fmaf(c0, t3.x, fmaf(c1, t3.y, fmaf(c2, t3.z, t3.w)));
    b00 = fminf(fminf(b00, sa0), sa1);   // -> v_min3_f32
    b01 = fminf(fminf(b01, sa2), sa3);
    b10 = fminf(fminf(b10, sc0), sc1);
    b11 = fminf(fminf(b11, sc2), sc3);
  }

  const float bestA = fminf(b00, b01);
  const float bestC = fminf(b10, b11);
  // partial layout: [dirb][split][N_]
  float* dst = partial + ((size_t)dirb * S + blockIdx.y) * N_;
  dst[qi0] = fmaxf(aq2 + bestA, 0.0f);
  dst[qi1] = fmaxf(cq2 + bestC, 0.0f);
}

__global__ __launch_bounds__(1024) void chamfer_finalize(
    const float* __restrict__ partial, float* __restrict__ out, int S) {
  float sum = 0.0f;
  const int total = 8 * N_;              // 65536 queries (both dirs)
  for (int f = threadIdx.x; f < total; f += 1024) {
    const int dirb = f >> 13;
    const int qi = f & (N_ - 1);
    const float* p = partial + (size_t)dirb * S * N_ + qi;
    float v = p[0];
    for (int s = 1; s < S; ++s) v = fminf(v, p[(size_t)s * N_]);
    sum += sqrtf(v);
  }
#pragma unroll
  for (int off = 32; off > 0; off >>= 1) sum += __shfl_down(sum, off, 64);
  __shared__ float ws[16];
  const int lane = threadIdx.x & 63;
  const int wid = threadIdx.x >> 6;
  if (lane == 0) ws[wid] = sum;
  __syncthreads();
  if (threadIdx.x == 0) {
    float t = 0.0f;
#pragma unroll
    for (int w = 0; w < 16; ++w) t += ws[w];
    out[0] = t * (1.0f / 32768.0f);      // /(B*N) per direction, N==M
  }
}

extern "C" void kernel_launch(void* const* d_in, const int* in_sizes, int n_in,
                              void* d_out, int out_size, void* d_ws, size_t ws_size,
                              hipStream_t stream) {
  const float* pred = (const float*)d_in[0];  // [B, N, 3]
  const float* gt   = (const float*)d_in[1];  // [B, M, 3]
  float* out = (float*)d_out;
  float* partial = (float*)d_ws;

  // partial needs 8 * S * N_ floats; pick S by available workspace.
  const int S = (ws_size >= (size_t)8 * 8 * N_ * sizeof(float)) ? 8 : 4;

  dim3 grid(N_ / (THREADS * QPT), S, 2 * B_);
  const size_t shbytes = (size_t)(N_ / S) * sizeof(float4);
  chamfer_min2<<<grid, THREADS, shbytes, stream>>>(pred, gt, partial);
  chamfer_finalize<<<1, 1024, 0, stream>>>(partial, out, S);
}

// Round 4
// 109.208 us; speedup vs baseline: 1.9641x; 1.9641x over previous
//
#include <hip/hip_runtime.h>

// Chamfer distance: B=4, N=M=8192, D=3, fp32. VALU compute-bound.
// min2: targets packed (x,y,z,|t|^2) in LDS (broadcast ds_read_b128),
//       4 queries/thread, score = 3 FMA/pair, split-partial stores.
// finalize: parallel (64 blocks) reduce-over-splits + sqrt + atomicAdd.

#define B_ 4
#define N_ 8192
#define QPT 4            // queries per thread
#define THREADS 256

// grid: (N/(THREADS*QPT), S, 2*B). Dynamic LDS: (N/S) float4.
__global__ __launch_bounds__(THREADS) void chamfer_min2(
    const float* __restrict__ pred, const float* __restrict__ gt,
    float* __restrict__ partial) {
  extern __shared__ float4 sh[];
  const int S = gridDim.y;
  const int TPB = N_ / S;                 // targets staged per block
  const int dirb = blockIdx.z;            // 0..7
  const int dir = dirb >> 2;              // 0: pred->gt, 1: gt->pred
  const int b = dirb & 3;

  const float* qsrc = (dir == 0 ? pred : gt) + (size_t)b * N_ * 3;
  const float* tsrc = (dir == 0 ? gt : pred) + (size_t)b * N_ * 3;

  // ---- stage TPB packed targets into LDS (|t|^2 computed on the fly) ----
  const float* tb = tsrc + (size_t)blockIdx.y * TPB * 3;
  for (int g = 0; g < TPB; g += THREADS * 4) {
    const int p0 = g + threadIdx.x * 4;
    if (p0 < TPB) {
      const float4 f0 = *(const float4*)(tb + 3 * p0);
      const float4 f1 = *(const float4*)(tb + 3 * p0 + 4);
      const float4 f2 = *(const float4*)(tb + 3 * p0 + 8);
      sh[p0 + 0] = make_float4(f0.x, f0.y, f0.z,
                               fmaf(f0.x, f0.x, fmaf(f0.y, f0.y, f0.z * f0.z)));
      sh[p0 + 1] = make_float4(f0.w, f1.x, f1.y,
                               fmaf(f0.w, f0.w, fmaf(f1.x, f1.x, f1.y * f1.y)));
      sh[p0 + 2] = make_float4(f1.z, f1.w, f2.x,
                               fmaf(f1.z, f1.z, fmaf(f1.w, f1.w, f2.x * f2.x)));
      sh[p0 + 3] = make_float4(f2.y, f2.z, f2.w,
                               fmaf(f2.y, f2.y, fmaf(f2.z, f2.z, f2.w * f2.w)));
    }
  }
  __syncthreads();

  // ---- four queries per thread ----
  const int qbase = blockIdx.x * (THREADS * QPT) + threadIdx.x;
  float nx[QPT], ny[QPT], nz[QPT], q2[QPT];
#pragma unroll
  for (int k = 0; k < QPT; ++k) {
    const int qi = qbase + k * THREADS;
    const float x = qsrc[3 * qi], y = qsrc[3 * qi + 1], z = qsrc[3 * qi + 2];
    nx[k] = -2.0f * x; ny[k] = -2.0f * y; nz[k] = -2.0f * z;
    q2[k] = fmaf(x, x, fmaf(y, y, z * z));
  }

  float acc0[QPT], acc1[QPT];
#pragma unroll
  for (int k = 0; k < QPT; ++k) { acc0[k] = 3.4e38f; acc1[k] = 3.4e38f; }

  for (int j = 0; j < TPB; j += 4) {
    const float4 t0 = sh[j + 0];
    const float4 t1 = sh[j + 1];
    const float4 t2 = sh[j + 2];
    const float4 t3 = sh[j + 3];
#pragma unroll
    for (int k = 0; k < QPT; ++k) {
      const float s0 = fmaf(nx[k], t0.x, fmaf(ny[k], t0.y, fmaf(nz[k], t0.z, t0.w)));
      const float s1 = fmaf(nx[k], t1.x, fmaf(ny[k], t1.y, fmaf(nz[k], t1.z, t1.w)));
      const float s2 = fmaf(nx[k], t2.x, fmaf(ny[k], t2.y, fmaf(nz[k], t2.z, t2.w)));
      const float s3 = fmaf(nx[k], t3.x, fmaf(ny[k], t3.y, fmaf(nz[k], t3.z, t3.w)));
      acc0[k] = fminf(fminf(acc0[k], s0), s1);   // -> v_min3_f32
      acc1[k] = fminf(fminf(acc1[k], s2), s3);
    }
  }

  // partial layout: [dirb][split][N_]
  float* dst = partial + ((size_t)dirb * S + blockIdx.y) * N_;
#pragma unroll
  for (int k = 0; k < QPT; ++k) {
    const int qi = qbase + k * THREADS;
    dst[qi] = fmaxf(q2[k] + fminf(acc0[k], acc1[k]), 0.0f);
  }
}

#define FBLOCKS 64
__global__ __launch_bounds__(256) void chamfer_finalize(
    const float* __restrict__ partial, float* __restrict__ out, int S) {
  float sum = 0.0f;
  const int total = 8 * N_;              // 65536 queries (both dirs)
  for (int f = blockIdx.x * 256 + threadIdx.x; f < total; f += FBLOCKS * 256) {
    const int dirb = f >> 13;
    const int qi = f & (N_ - 1);
    const float* p = partial + (size_t)dirb * S * N_ + qi;
    float v = p[0];
    for (int s = 1; s < S; ++s) v = fminf(v, p[(size_t)s * N_]);
    sum += sqrtf(v);
  }
#pragma unroll
  for (int off = 32; off > 0; off >>= 1) sum += __shfl_down(sum, off, 64);
  __shared__ float ws[4];
  const int lane = threadIdx.x & 63;
  const int wid = threadIdx.x >> 6;
  if (lane == 0) ws[wid] = sum;
  __syncthreads();
  if (threadIdx.x == 0) {
    atomicAdd(out, ((ws[0] + ws[1]) + (ws[2] + ws[3])) * (1.0f / 32768.0f));
  }
}

extern "C" void kernel_launch(void* const* d_in, const int* in_sizes, int n_in,
                              void* d_out, int out_size, void* d_ws, size_t ws_size,
                              hipStream_t stream) {
  const float* pred = (const float*)d_in[0];  // [B, N, 3]
  const float* gt   = (const float*)d_in[1];  // [B, M, 3]
  float* out = (float*)d_out;
  float* partial = (float*)d_ws;

  // partial needs 8 * S * N_ floats.
  int S = 4;
  if (ws_size >= (size_t)8 * 16 * N_ * sizeof(float)) S = 16;
  else if (ws_size >= (size_t)8 * 8 * N_ * sizeof(float)) S = 8;

  hipMemsetAsync(out, 0, sizeof(float), stream);

  dim3 grid(N_ / (THREADS * QPT), S, 2 * B_);
  const size_t shbytes = (size_t)(N_ / S) * sizeof(float4);
  chamfer_min2<<<grid, THREADS, shbytes, stream>>>(pred, gt, partial);
  chamfer_finalize<<<FBLOCKS, 256, 0, stream>>>(partial, out, S);
}

// Round 5
// 103.227 us; speedup vs baseline: 2.0779x; 1.0579x over previous
//
#include <hip/hip_runtime.h>

// Chamfer distance: B=4, N=M=8192, D=3, fp32. VALU issue-bound.
// Symmetric kernel: each pair (n,m) computed ONCE; feeds both row-min
// (pred->gt) and col-min (gt->pred). ~5.3 issues/pair vs 7.0 for the
// two-directional version. v_min3_f32 forced via inline asm.

#define B_ 4
#define N_ 8192
#define TM 1024
#define SM (N_ / TM)   // 8 col-tiles
#define THREADS 512
#define CSN 8          // col strips per tile (TM / 128)

__device__ __forceinline__ float min3f(float a, float b, float c) {
  float d;
  asm("v_min3_f32 %0, %1, %2, %3" : "=v"(d) : "v"(a), "v"(b), "v"(c));
  return d;
}

// grid: (SM, SN, B_). 512 threads = 16 (i, rows) x 32 (j, cols).
// Per block tile: TN x TM. Row chunks of 64 (16i x 4r); col strips of 128 (32j x 4c).
template<int RC>
__global__ __launch_bounds__(THREADS) void chamfer_sym(
    const float* __restrict__ pred, const float* __restrict__ gt,
    float* __restrict__ rowpart, float* __restrict__ colpart,
    float* __restrict__ accws) {
  constexpr int TN = RC * 64;
  constexpr int SN = N_ / TN;
  __shared__ float4 mlds[TM];    // 16 KB: packed (x,y,z,|t|^2)
  __shared__ float sbuf[4096];   // 16 KB: rowlds 2x[32][64]  /  collds [16][256]

  const int b  = blockIdx.z;
  const int tn = blockIdx.y;
  const int tm = blockIdx.x;
  const int tid = threadIdx.x;
  const int i = tid & 15;
  const int j = tid >> 4;

  if (tm == 0 && tn == 0 && b == 0 && tid == 0) {
    atomicExch(&accws[0], 0.0f);
    atomicExch(((unsigned int*)accws) + 1, 0u);
  }

  const float* qsrc = pred + (size_t)b * N_ * 3;  // rows = pred points
  const float* tsrc = gt   + (size_t)b * N_ * 3;  // cols = gt points

  // ---- stage m-tile (1024 points) packed into LDS ----
  if (tid < 256) {
    const float* tb = tsrc + (size_t)tm * TM * 3;
    const int p0 = tid * 4;
    const float4 f0 = *(const float4*)(tb + 3 * p0);
    const float4 f1 = *(const float4*)(tb + 3 * p0 + 4);
    const float4 f2 = *(const float4*)(tb + 3 * p0 + 8);
    mlds[p0+0] = make_float4(f0.x,f0.y,f0.z, fmaf(f0.x,f0.x,fmaf(f0.y,f0.y,f0.z*f0.z)));
    mlds[p0+1] = make_float4(f0.w,f1.x,f1.y, fmaf(f0.w,f0.w,fmaf(f1.x,f1.x,f1.y*f1.y)));
    mlds[p0+2] = make_float4(f1.z,f1.w,f2.x, fmaf(f1.z,f1.z,fmaf(f1.w,f1.w,f2.x*f2.x)));
    mlds[p0+3] = make_float4(f2.y,f2.z,f2.w, fmaf(f2.y,f2.y,fmaf(f2.z,f2.z,f2.w*f2.w)));
  }

  float colacc[32];
#pragma unroll
  for (int c = 0; c < 32; ++c) colacc[c] = 3.4e38f;

  __syncthreads();

  const int nbase = tn * TN;

  for (int rc = 0; rc < RC; ++rc) {
    // this thread's 4 q-points, direct from global (48B-aligned; L1 broadcast across j)
    const float* qb = qsrc + (size_t)(nbase + rc * 64 + i * 4) * 3;
    const float4 g0 = *(const float4*)(qb);
    const float4 g1 = *(const float4*)(qb + 4);
    const float4 g2 = *(const float4*)(qb + 8);
    const float qx[4] = {g0.x, g0.w, g1.z, g2.y};
    const float qy[4] = {g0.y, g1.x, g1.w, g2.z};
    const float qz[4] = {g0.z, g1.y, g2.x, g2.w};
    float nx[4], ny[4], nz[4], q2[4], racc[4];
#pragma unroll
    for (int r = 0; r < 4; ++r) {
      nx[r] = -2.0f * qx[r]; ny[r] = -2.0f * qy[r]; nz[r] = -2.0f * qz[r];
      q2[r] = fmaf(qx[r],qx[r], fmaf(qy[r],qy[r], qz[r]*qz[r]));
      racc[r] = 3.4e38f;
    }

#pragma unroll
    for (int cs = 0; cs < CSN; ++cs) {
      const int mb = cs * 128 + j * 4;
      const float4 t0 = mlds[mb+0];
      const float4 t1 = mlds[mb+1];
      const float4 t2 = mlds[mb+2];
      const float4 t3 = mlds[mb+3];
      float s[4][4];
#pragma unroll
      for (int r = 0; r < 4; ++r) {
        s[r][0] = fmaf(nx[r],t0.x, fmaf(ny[r],t0.y, fmaf(nz[r],t0.z, t0.w)));
        s[r][1] = fmaf(nx[r],t1.x, fmaf(ny[r],t1.y, fmaf(nz[r],t1.z, t1.w)));
        s[r][2] = fmaf(nx[r],t2.x, fmaf(ny[r],t2.y, fmaf(nz[r],t2.z, t2.w)));
        s[r][3] = fmaf(nx[r],t3.x, fmaf(ny[r],t3.y, fmaf(nz[r],t3.z, t3.w)));
        racc[r] = min3f(racc[r], s[r][0], s[r][1]);
        racc[r] = min3f(racc[r], s[r][2], s[r][3]);
      }
#pragma unroll
      for (int c = 0; c < 4; ++c) {
        colacc[cs*4+c] = min3f(colacc[cs*4+c], s[0][c] + q2[0], s[1][c] + q2[1]);
        colacc[cs*4+c] = min3f(colacc[cs*4+c], s[2][c] + q2[2], s[3][c] + q2[3]);
      }
    }

    // ---- flush row partials (double-buffered, one barrier per chunk) ----
    const int buf = (rc & 1) * 2048;
#pragma unroll
    for (int r = 0; r < 4; ++r) sbuf[buf + j*64 + i*4 + r] = racc[r] + q2[r];
    __syncthreads();
    {
      const int row = tid >> 3, g = tid & 7;
      const float v0 = sbuf[buf + (g*4+0)*64 + row];
      const float v1 = sbuf[buf + (g*4+1)*64 + row];
      const float v2 = sbuf[buf + (g*4+2)*64 + row];
      const float v3 = sbuf[buf + (g*4+3)*64 + row];
      float v = fminf(min3f(v0, v1, v2), v3);
      v = fminf(v, __shfl_xor(v, 1, 64));
      v = fminf(v, __shfl_xor(v, 2, 64));
      v = fminf(v, __shfl_xor(v, 4, 64));
      if (g == 0)
        rowpart[((size_t)b * SM + tm) * N_ + nbase + rc*64 + row] = v;
    }
  }

  // ---- col partial reduce across i (4 passes of 256 cols) ----
  __syncthreads();
#pragma unroll
  for (int p = 0; p < 4; ++p) {
#pragma unroll
    for (int k = 0; k < 8; ++k) {  // cs in {2p,2p+1}, c in 0..3
      sbuf[i*256 + (k>>2)*128 + j*4 + (k&3)] = colacc[(2*p + (k>>2))*4 + (k&3)];
    }
    __syncthreads();
    if (tid < 256) {
      float v = sbuf[tid];
#pragma unroll
      for (int ii = 1; ii <= 13; ii += 2)
        v = min3f(v, sbuf[ii*256 + tid], sbuf[(ii+1)*256 + tid]);
      v = fminf(v, sbuf[15*256 + tid]);
      colpart[((size_t)b * SN + tn) * N_ + tm*TM + p*256 + tid] = v;
    }
    __syncthreads();
  }
}

template<int SN>
__global__ __launch_bounds__(256) void chamfer_fin(
    const float* __restrict__ rowpart, const float* __restrict__ colpart,
    float* __restrict__ accws, float* __restrict__ out) {
  const int t = blockIdx.x * 256 + threadIdx.x;   // 0..32767
  const int b = t >> 13;
  const int n = t & (N_ - 1);
  float v = rowpart[(size_t)(b * SM) * N_ + n];
#pragma unroll
  for (int s = 1; s < SM; ++s) v = fminf(v, rowpart[(size_t)(b*SM + s) * N_ + n]);
  float sum = sqrtf(fmaxf(v, 0.0f));
  float w = colpart[(size_t)(b * SN) * N_ + n];
#pragma unroll
  for (int s = 1; s < SN; ++s) w = fminf(w, colpart[(size_t)(b*SN + s) * N_ + n]);
  sum += sqrtf(fmaxf(w, 0.0f));
#pragma unroll
  for (int off = 32; off > 0; off >>= 1) sum += __shfl_down(sum, off, 64);
  __shared__ float ws4[4];
  const int lane = threadIdx.x & 63, wid = threadIdx.x >> 6;
  if (lane == 0) ws4[wid] = sum;
  __syncthreads();
  if (threadIdx.x == 0) {
    const float bs = (ws4[0] + ws4[1]) + (ws4[2] + ws4[3]);
    atomicAdd(&accws[0], bs);
    __threadfence();
    const unsigned old = atomicAdd(((unsigned int*)accws) + 1, 1u);
    if (old == gridDim.x - 1) {
      __threadfence();
      const float tot = atomicAdd(&accws[0], 0.0f);
      out[0] = tot * (1.0f / 32768.0f);   // /(B*N) per direction, N==M
    }
  }
}

extern "C" void kernel_launch(void* const* d_in, const int* in_sizes, int n_in,
                              void* d_out, int out_size, void* d_ws, size_t ws_size,
                              hipStream_t stream) {
  const float* pred = (const float*)d_in[0];  // [B, N, 3]
  const float* gt   = (const float*)d_in[1];  // [B, M, 3]
  float* out = (float*)d_out;
  float* rowpart = (float*)d_ws;
  const size_t rowfl = (size_t)B_ * SM * N_;  // 262144 floats (1 MB)
  const size_t base = rowfl * sizeof(float) + 64;

#define LAUNCH(RCV)                                                            \
  {                                                                            \
    constexpr int SNV = N_ / (RCV * 64);                                       \
    float* colpart = rowpart + rowfl;                                          \
    float* accws = colpart + (size_t)B_ * SNV * N_;                            \
    chamfer_sym<RCV><<<dim3(SM, SNV, B_), THREADS, 0, stream>>>(               \
        pred, gt, rowpart, colpart, accws);                                    \
    chamfer_fin<SNV><<<128, 256, 0, stream>>>(rowpart, colpart, accws, out);   \
  }

  if      (ws_size >= base + (size_t)B_ * 8 * N_ * sizeof(float)) LAUNCH(16)
  else if (ws_size >= base + (size_t)B_ * 4 * N_ * sizeof(float)) LAUNCH(32)
  else if (ws_size >= base + (size_t)B_ * 2 * N_ * sizeof(float)) LAUNCH(64)
  else                                                            LAUNCH(128)
#undef LAUNCH
}